// Round 2
// baseline (2605.917 us; speedup 1.0000x reference)
//
#include <hip/hip_runtime.h>
#include <stdint.h>

// FrequencySemanticCipher: enc = image + idwt(noise/maxabs), then per-batch min-max norm.
// PRNG: JAX threefry2x32, jax_threefry_partitionable=True semantics.
//   subkey_i = threefry((0,123), (0,i)) -> (bits1, bits2)  [split_foldlike: raw pair]
//   bits[i]  = bits1 ^ bits2 of threefry(subkey, (hi=0, lo=i))  [32-bit draw folds both words]

#define NSUB 6291456u      // 32*3*256*256 elements per subband
#define CHW4 196608        // 3*512*512/4 (float4 per batch)

struct U2 { uint32_t x, y; };

__device__ __forceinline__ U2 threefry(uint32_t k0, uint32_t k1, uint32_t x0, uint32_t x1) {
  uint32_t ks2 = k0 ^ k1 ^ 0x1BD11BDAu;
  x0 += k0; x1 += k1;
#define TF_R(r) { x0 += x1; x1 = (x1 << (r)) | (x1 >> (32 - (r))); x1 ^= x0; }
  TF_R(13) TF_R(15) TF_R(26) TF_R(6)
  x0 += k1; x1 += ks2 + 1u;
  TF_R(17) TF_R(29) TF_R(16) TF_R(24)
  x0 += ks2; x1 += k0 + 2u;
  TF_R(13) TF_R(15) TF_R(26) TF_R(6)
  x0 += k0; x1 += k1 + 3u;
  TF_R(17) TF_R(29) TF_R(16) TF_R(24)
  x0 += k1; x1 += ks2 + 4u;
  TF_R(13) TF_R(15) TF_R(26) TF_R(6)
  x0 += ks2; x1 += k0 + 5u;
#undef TF_R
  U2 r; r.x = x0; r.y = x1; return r;
}

__device__ __forceinline__ uint32_t threefry_fold(uint32_t k0, uint32_t k1, uint32_t x1) {
  U2 r = threefry(k0, k1, 0u, x1);
  return r.x ^ r.y;   // partitionable 32-bit draw: bits1 ^ bits2
}

// XLA ErfInv32 (Giles) polynomial
__device__ __forceinline__ float erfinv_f32(float x) {
  float w = -logf(1.0f - x * x);
  float p;
  if (w < 5.0f) {
    w = w - 2.5f;
    p = 2.81022636e-08f;
    p = fmaf(p, w, 3.43273939e-07f);
    p = fmaf(p, w, -3.5233877e-06f);
    p = fmaf(p, w, -4.39150654e-06f);
    p = fmaf(p, w, 0.00021858087f);
    p = fmaf(p, w, -0.00125372503f);
    p = fmaf(p, w, -0.00417768164f);
    p = fmaf(p, w, 0.246640727f);
    p = fmaf(p, w, 1.50140941f);
  } else {
    w = sqrtf(w) - 3.0f;
    p = -0.000200214257f;
    p = fmaf(p, w, 0.000100950558f);
    p = fmaf(p, w, 0.00134934322f);
    p = fmaf(p, w, -0.00367342844f);
    p = fmaf(p, w, 0.00573950773f);
    p = fmaf(p, w, -0.0076224613f);
    p = fmaf(p, w, 0.00943887047f);
    p = fmaf(p, w, 1.00167406f);
    p = fmaf(p, w, 2.83297682f);
  }
  return p * x;
}

__device__ __forceinline__ float normal_from_bits(uint32_t bits) {
  uint32_t fb = (bits >> 9) | 0x3f800000u;
  float f = __uint_as_float(fb) - 1.0f;      // [0,1)
  const float lo = -0.99999994f;             // nextafter(-1,0); (hi-lo) rounds to exactly 2.0f
  float u = fmaxf(lo, f * 2.0f + lo);
  return 1.41421354f * erfinv_f32(u);        // float(sqrt(2)) * erfinv
}

// order-preserving float<->uint map (for atomic min/max on signed floats)
__device__ __forceinline__ uint32_t map_ord(float f) {
  uint32_t s = __float_as_uint(f);
  return (s & 0x80000000u) ? ~s : (s | 0x80000000u);
}
__device__ __forceinline__ float unmap_ord(uint32_t u) {
  return (u & 0x80000000u) ? __uint_as_float(u ^ 0x80000000u) : __uint_as_float(~u);
}

// ws layout (uint32 words):
// [0..7]   subkeys (LL0,LL1, LH0,LH1, HL0,HL1, HH0,HH1)
// [8..11]  per-subband folded-bits max   (init 0)
// [12..15] per-subband folded-bits min   (init 0xFFFFFFFF)
// [16..19] per-subband 1/(maxabs+eps) as float
// [20..51] per-batch mapped min (init 0xFFFFFFFF)
// [52..83] per-batch mapped max (init 0)
// [84..115]  per-batch min (float)
// [116..147] per-batch 1/scale (float)

__global__ void k_init(uint32_t* ws) {
  int t = threadIdx.x;
  if (t == 0) {
    for (int i = 0; i < 4; ++i) {
      U2 r = threefry(0u, 123u, 0u, (uint32_t)i);
      ws[2 * i] = r.x;
      ws[2 * i + 1] = r.y;
    }
  }
  if (t < 4)  ws[8 + t] = 0u;
  if (t < 4)  ws[12 + t] = 0xFFFFFFFFu;
  if (t < 32) ws[20 + t] = 0xFFFFFFFFu;
  if (t < 32) ws[52 + t] = 0u;
}

// K1: per-subband min/max of folded bits (monotone proxy for max|normal|)
__global__ __launch_bounds__(256) void k_noise_minmax(uint32_t* __restrict__ ws) {
  const int s = blockIdx.y;
  const uint32_t k0 = ws[2 * s], k1 = ws[2 * s + 1];
  const uint32_t i = blockIdx.x * 256u + threadIdx.x;
  uint32_t b = threefry_fold(k0, k1, i);
  uint32_t bmax = b, bmin = b;
  #pragma unroll
  for (int off = 32; off > 0; off >>= 1) {
    bmax = max(bmax, (uint32_t)__shfl_down(bmax, off));
    bmin = min(bmin, (uint32_t)__shfl_down(bmin, off));
  }
  __shared__ uint32_t smax[4], smin[4];
  const int lane = threadIdx.x & 63, w = threadIdx.x >> 6;
  if (lane == 0) { smax[w] = bmax; smin[w] = bmin; }
  __syncthreads();
  if (threadIdx.x == 0) {
    bmax = max(max(smax[0], smax[1]), max(smax[2], smax[3]));
    bmin = min(min(smin[0], smin[1]), min(smin[2], smin[3]));
    atomicMax(&ws[8 + s], bmax);
    atomicMin(&ws[12 + s], bmin);
  }
}

__global__ void k_scales(uint32_t* ws) {
  int s = threadIdx.x;
  if (s < 4) {
    float nmax = normal_from_bits(ws[8 + s]);
    float nmin = normal_from_bits(ws[12 + s]);
    float mabs = fmaxf(nmax, -nmin);
    ((float*)ws)[16 + s] = 1.0f / (mabs + 1e-8f);
  }
}

// K2: enc = image + idwt(scaled noise); per-batch min/max reduction
__global__ __launch_bounds__(256) void k_enc(const float* __restrict__ img,
                                             float* __restrict__ out,
                                             uint32_t* __restrict__ ws) {
  const int j = threadIdx.x;       // 0..255
  const int i = blockIdx.x;        // 0..255
  const int c = blockIdx.y;        // 0..2
  const int b = blockIdx.z;        // 0..31
  const uint32_t idx = ((uint32_t)(b * 3 + c) << 16) | ((uint32_t)i << 8) | (uint32_t)j;
  const float* wsf = (const float*)ws;
  float n0 = normal_from_bits(threefry_fold(ws[0], ws[1], idx)) * wsf[16];
  float n1 = normal_from_bits(threefry_fold(ws[2], ws[3], idx)) * wsf[17];
  float n2 = normal_from_bits(threefry_fold(ws[4], ws[5], idx)) * wsf[18];
  float n3 = normal_from_bits(threefry_fold(ws[6], ws[7], idx)) * wsf[19];
  float qa = 0.5f * (n0 + n1 + n2 + n3);
  float qb = 0.5f * (n0 + n1 - n2 - n3);
  float qc = 0.5f * (n0 - n1 + n2 - n3);
  float qd = 0.5f * (n0 - n1 - n2 + n3);
  size_t base = ((size_t)(b * 3 + c) * 512 + 2 * i) * 512 + 2 * j;
  const float2 r0 = *(const float2*)(img + base);
  const float2 r1 = *(const float2*)(img + base + 512);
  float e00 = r0.x + qa, e01 = r0.y + qb, e10 = r1.x + qc, e11 = r1.y + qd;
  *(float2*)(out + base) = make_float2(e00, e01);
  *(float2*)(out + base + 512) = make_float2(e10, e11);
  float vmin = fminf(fminf(e00, e01), fminf(e10, e11));
  float vmax = fmaxf(fmaxf(e00, e01), fmaxf(e10, e11));
  #pragma unroll
  for (int off = 32; off > 0; off >>= 1) {
    vmin = fminf(vmin, __shfl_down(vmin, off));
    vmax = fmaxf(vmax, __shfl_down(vmax, off));
  }
  __shared__ float smin[4], smax[4];
  const int lane = threadIdx.x & 63, w = threadIdx.x >> 6;
  if (lane == 0) { smin[w] = vmin; smax[w] = vmax; }
  __syncthreads();
  if (threadIdx.x == 0) {
    vmin = fminf(fminf(smin[0], smin[1]), fminf(smin[2], smin[3]));
    vmax = fmaxf(fmaxf(smax[0], smax[1]), fmaxf(smax[2], smax[3]));
    atomicMin(&ws[20 + b], map_ord(vmin));
    atomicMax(&ws[52 + b], map_ord(vmax));
  }
}

__global__ void k_batch_scale(uint32_t* ws) {
  int b = threadIdx.x;
  if (b < 32) {
    float mn = unmap_ord(ws[20 + b]);
    float mx = unmap_ord(ws[52 + b]);
    ((float*)ws)[84 + b] = mn;
    ((float*)ws)[116 + b] = 1.0f / fmaxf(mx - mn, 1e-8f);
  }
}

// K3: in-place per-batch min-max normalize, float4 per thread
__global__ __launch_bounds__(256) void k_norm(float* __restrict__ out,
                                              const uint32_t* __restrict__ ws) {
  const int idx = blockIdx.x * 256 + threadIdx.x;   // float4 index, < 6291456
  const int b = idx / CHW4;
  const float mn = ((const float*)ws)[84 + b];
  const float inv = ((const float*)ws)[116 + b];
  float4 v = ((float4*)out)[idx];
  v.x = (v.x - mn) * inv;
  v.y = (v.y - mn) * inv;
  v.z = (v.z - mn) * inv;
  v.w = (v.w - mn) * inv;
  ((float4*)out)[idx] = v;
}

extern "C" void kernel_launch(void* const* d_in, const int* in_sizes, int n_in,
                              void* d_out, int out_size, void* d_ws, size_t ws_size,
                              hipStream_t stream) {
  const float* img = (const float*)d_in[0];
  float* out = (float*)d_out;
  uint32_t* ws = (uint32_t*)d_ws;

  k_init<<<1, 128, 0, stream>>>(ws);
  k_noise_minmax<<<dim3(NSUB / 256, 4, 1), 256, 0, stream>>>(ws);
  k_scales<<<1, 64, 0, stream>>>(ws);
  k_enc<<<dim3(256, 3, 32), 256, 0, stream>>>(img, out, ws);
  k_batch_scale<<<1, 64, 0, stream>>>(ws);
  k_norm<<<NSUB / 256, 256, 0, stream>>>(out, ws);
}

// Round 3
// 282.312 us; speedup vs baseline: 9.2306x; 9.2306x over previous
//
#include <hip/hip_runtime.h>
#include <stdint.h>

// FrequencySemanticCipher: enc = image + idwt(noise/maxabs), then per-batch min-max norm.
// PRNG: JAX threefry2x32, jax_threefry_partitionable=True semantics.
//   subkey_i = threefry((0,123), (0,i)) -> (bits1, bits2)
//   bits[i]  = bits1 ^ bits2 of threefry(subkey, (0, i))
//
// R2 lesson [counters]: device-scope atomics resolve at memory-side fabric
// (WRITE_SIZE showed 32B/atomic to HBM, ~11ns serialized per address).
// => minimize atomic count, give each atomic target its own 64B line.

#define NSUB 6291456u      // 32*3*256*256 elements per subband
#define CHW4 196608        // 3*512*512/4 (float4 per batch)
#define EPT  64            // elements per thread in k_noise_minmax

struct U2 { uint32_t x, y; };

__device__ __forceinline__ U2 threefry(uint32_t k0, uint32_t k1, uint32_t x0, uint32_t x1) {
  uint32_t ks2 = k0 ^ k1 ^ 0x1BD11BDAu;
  x0 += k0; x1 += k1;
#define TF_R(r) { x0 += x1; x1 = (x1 << (r)) | (x1 >> (32 - (r))); x1 ^= x0; }
  TF_R(13) TF_R(15) TF_R(26) TF_R(6)
  x0 += k1; x1 += ks2 + 1u;
  TF_R(17) TF_R(29) TF_R(16) TF_R(24)
  x0 += ks2; x1 += k0 + 2u;
  TF_R(13) TF_R(15) TF_R(26) TF_R(6)
  x0 += k0; x1 += k1 + 3u;
  TF_R(17) TF_R(29) TF_R(16) TF_R(24)
  x0 += k1; x1 += ks2 + 4u;
  TF_R(13) TF_R(15) TF_R(26) TF_R(6)
  x0 += ks2; x1 += k0 + 5u;
#undef TF_R
  U2 r; r.x = x0; r.y = x1; return r;
}

__device__ __forceinline__ uint32_t threefry_fold(uint32_t k0, uint32_t k1, uint32_t x1) {
  U2 r = threefry(k0, k1, 0u, x1);
  return r.x ^ r.y;
}

// XLA ErfInv32 (Giles) polynomial
__device__ __forceinline__ float erfinv_f32(float x) {
  float w = -logf(1.0f - x * x);
  float p;
  if (w < 5.0f) {
    w = w - 2.5f;
    p = 2.81022636e-08f;
    p = fmaf(p, w, 3.43273939e-07f);
    p = fmaf(p, w, -3.5233877e-06f);
    p = fmaf(p, w, -4.39150654e-06f);
    p = fmaf(p, w, 0.00021858087f);
    p = fmaf(p, w, -0.00125372503f);
    p = fmaf(p, w, -0.00417768164f);
    p = fmaf(p, w, 0.246640727f);
    p = fmaf(p, w, 1.50140941f);
  } else {
    w = sqrtf(w) - 3.0f;
    p = -0.000200214257f;
    p = fmaf(p, w, 0.000100950558f);
    p = fmaf(p, w, 0.00134934322f);
    p = fmaf(p, w, -0.00367342844f);
    p = fmaf(p, w, 0.00573950773f);
    p = fmaf(p, w, -0.0076224613f);
    p = fmaf(p, w, 0.00943887047f);
    p = fmaf(p, w, 1.00167406f);
    p = fmaf(p, w, 2.83297682f);
  }
  return p * x;
}

__device__ __forceinline__ float normal_from_bits(uint32_t bits) {
  uint32_t fb = (bits >> 9) | 0x3f800000u;
  float f = __uint_as_float(fb) - 1.0f;      // [0,1)
  const float lo = -0.99999994f;
  float u = fmaxf(lo, f * 2.0f + lo);
  return 1.41421354f * erfinv_f32(u);
}

// order-preserving float<->uint map
__device__ __forceinline__ uint32_t map_ord(float f) {
  uint32_t s = __float_as_uint(f);
  return (s & 0x80000000u) ? ~s : (s | 0x80000000u);
}
__device__ __forceinline__ float unmap_ord(uint32_t u) {
  return (u & 0x80000000u) ? __uint_as_float(u ^ 0x80000000u) : __uint_as_float(~u);
}

// ws layout (uint32 words) — every atomic target on its own 64B line:
// [0..7]            subkeys
// [16 + 16*s]       subband folded-bits max   (s<4, init 0)
// [80 + 16*s]       subband folded-bits min   (s<4, init 0xFFFFFFFF)
// [144..147]        subband 1/(maxabs+eps)    (float, non-atomic)
// [160 + 32*b]      batch mapped min          (b<32, init 0xFFFFFFFF)
// [160 + 32*b + 16] batch mapped max          (b<32, init 0)
// [1184 + b]        batch min (float)
// [1216 + b]        batch 1/scale (float)

__global__ void k_init(uint32_t* ws) {
  int t = threadIdx.x;
  if (t == 0) {
    for (int i = 0; i < 4; ++i) {
      U2 r = threefry(0u, 123u, 0u, (uint32_t)i);
      ws[2 * i] = r.x;
      ws[2 * i + 1] = r.y;
    }
  }
  if (t < 4) {
    ws[16 + 16 * t] = 0u;
    ws[80 + 16 * t] = 0xFFFFFFFFu;
  }
  if (t < 32) {
    ws[160 + 32 * t] = 0xFFFFFFFFu;
    ws[160 + 32 * t + 16] = 0u;
  }
}

// K1: per-subband min/max of folded bits. 64 elems/thread -> 1536 blocks, 3072 atomics.
__global__ __launch_bounds__(256) void k_noise_minmax(uint32_t* __restrict__ ws) {
  const int s = blockIdx.y;
  const uint32_t k0 = ws[2 * s], k1 = ws[2 * s + 1];
  const uint32_t base = blockIdx.x * (256u * EPT) + threadIdx.x;
  uint32_t bmax = 0u, bmin = 0xFFFFFFFFu;
  #pragma unroll 8
  for (int k = 0; k < EPT; ++k) {
    uint32_t b = threefry_fold(k0, k1, base + (uint32_t)k * 256u);
    bmax = max(bmax, b);
    bmin = min(bmin, b);
  }
  #pragma unroll
  for (int off = 32; off > 0; off >>= 1) {
    bmax = max(bmax, (uint32_t)__shfl_down(bmax, off));
    bmin = min(bmin, (uint32_t)__shfl_down(bmin, off));
  }
  __shared__ uint32_t smax[4], smin[4];
  const int lane = threadIdx.x & 63, w = threadIdx.x >> 6;
  if (lane == 0) { smax[w] = bmax; smin[w] = bmin; }
  __syncthreads();
  if (threadIdx.x == 0) {
    bmax = max(max(smax[0], smax[1]), max(smax[2], smax[3]));
    bmin = min(min(smin[0], smin[1]), min(smin[2], smin[3]));
    atomicMax(&ws[16 + 16 * s], bmax);
    atomicMin(&ws[80 + 16 * s], bmin);
  }
}

__global__ void k_scales(uint32_t* ws) {
  int s = threadIdx.x;
  if (s < 4) {
    float nmax = normal_from_bits(ws[16 + 16 * s]);
    float nmin = normal_from_bits(ws[80 + 16 * s]);
    float mabs = fmaxf(nmax, -nmin);
    ((float*)ws)[144 + s] = 1.0f / (mabs + 1e-8f);
  }
}

// K2: enc = image + idwt(scaled noise); per-batch min/max reduction
__global__ __launch_bounds__(256) void k_enc(const float* __restrict__ img,
                                             float* __restrict__ out,
                                             uint32_t* __restrict__ ws) {
  const int j = threadIdx.x;       // 0..255
  const int i = blockIdx.x;        // 0..255
  const int c = blockIdx.y;        // 0..2
  const int b = blockIdx.z;        // 0..31
  const uint32_t idx = ((uint32_t)(b * 3 + c) << 16) | ((uint32_t)i << 8) | (uint32_t)j;
  const float* wsf = (const float*)ws;
  float n0 = normal_from_bits(threefry_fold(ws[0], ws[1], idx)) * wsf[144];
  float n1 = normal_from_bits(threefry_fold(ws[2], ws[3], idx)) * wsf[145];
  float n2 = normal_from_bits(threefry_fold(ws[4], ws[5], idx)) * wsf[146];
  float n3 = normal_from_bits(threefry_fold(ws[6], ws[7], idx)) * wsf[147];
  float qa = 0.5f * (n0 + n1 + n2 + n3);
  float qb = 0.5f * (n0 + n1 - n2 - n3);
  float qc = 0.5f * (n0 - n1 + n2 - n3);
  float qd = 0.5f * (n0 - n1 - n2 + n3);
  size_t base = ((size_t)(b * 3 + c) * 512 + 2 * i) * 512 + 2 * j;
  const float2 r0 = *(const float2*)(img + base);
  const float2 r1 = *(const float2*)(img + base + 512);
  float e00 = r0.x + qa, e01 = r0.y + qb, e10 = r1.x + qc, e11 = r1.y + qd;
  *(float2*)(out + base) = make_float2(e00, e01);
  *(float2*)(out + base + 512) = make_float2(e10, e11);
  float vmin = fminf(fminf(e00, e01), fminf(e10, e11));
  float vmax = fmaxf(fmaxf(e00, e01), fmaxf(e10, e11));
  #pragma unroll
  for (int off = 32; off > 0; off >>= 1) {
    vmin = fminf(vmin, __shfl_down(vmin, off));
    vmax = fmaxf(vmax, __shfl_down(vmax, off));
  }
  __shared__ float smin[4], smax[4];
  const int lane = threadIdx.x & 63, w = threadIdx.x >> 6;
  if (lane == 0) { smin[w] = vmin; smax[w] = vmax; }
  __syncthreads();
  if (threadIdx.x == 0) {
    vmin = fminf(fminf(smin[0], smin[1]), fminf(smin[2], smin[3]));
    vmax = fmaxf(fmaxf(smax[0], smax[1]), fmaxf(smax[2], smax[3]));
    atomicMin(&ws[160 + 32 * b], map_ord(vmin));
    atomicMax(&ws[160 + 32 * b + 16], map_ord(vmax));
  }
}

__global__ void k_batch_scale(uint32_t* ws) {
  int b = threadIdx.x;
  if (b < 32) {
    float mn = unmap_ord(ws[160 + 32 * b]);
    float mx = unmap_ord(ws[160 + 32 * b + 16]);
    ((float*)ws)[1184 + b] = mn;
    ((float*)ws)[1216 + b] = 1.0f / fmaxf(mx - mn, 1e-8f);
  }
}

// K3: in-place per-batch min-max normalize, float4 per thread
__global__ __launch_bounds__(256) void k_norm(float* __restrict__ out,
                                              const uint32_t* __restrict__ ws) {
  const int idx = blockIdx.x * 256 + threadIdx.x;   // float4 index, < 6291456
  const int b = idx / CHW4;
  const float mn = ((const float*)ws)[1184 + b];
  const float inv = ((const float*)ws)[1216 + b];
  float4 v = ((float4*)out)[idx];
  v.x = (v.x - mn) * inv;
  v.y = (v.y - mn) * inv;
  v.z = (v.z - mn) * inv;
  v.w = (v.w - mn) * inv;
  ((float4*)out)[idx] = v;
}

extern "C" void kernel_launch(void* const* d_in, const int* in_sizes, int n_in,
                              void* d_out, int out_size, void* d_ws, size_t ws_size,
                              hipStream_t stream) {
  const float* img = (const float*)d_in[0];
  float* out = (float*)d_out;
  uint32_t* ws = (uint32_t*)d_ws;

  k_init<<<1, 64, 0, stream>>>(ws);
  k_noise_minmax<<<dim3(NSUB / (256 * EPT), 4, 1), 256, 0, stream>>>(ws);
  k_scales<<<1, 64, 0, stream>>>(ws);
  k_enc<<<dim3(256, 3, 32), 256, 0, stream>>>(img, out, ws);
  k_batch_scale<<<1, 64, 0, stream>>>(ws);
  k_norm<<<NSUB / 256, 256, 0, stream>>>(out, ws);
}